// Round 5
// baseline (35.530 us; speedup 1.0000x reference)
//
#include <hip/hip_runtime.h>
#include <hip/hip_bf16.h>

// RotT: M = expm(-0.5i*angle*S), S = |0><1|+|1><0| on qudit 7 of 15 qutrits.
// M = [[c,-is,0],[-is,c,0],[0,0,1]], c=cos(angle/2), s=sin(angle/2).
// Both rotated planes obey the same formula:
//   y(e) = c*x(e) + s*(xi(partner), -xr(partner)),  partner = e -/+ 2187
// Plane 2 is passthrough.
//
// Output (verified round 4): 2*D bfloat16, interleaved IMAG-FIRST:
//   u32 per amplitude = (bf16(re) << 16) | bf16(im).
//
// Round-4 kernel: 32.7 us with 4B scalar accesses = 84% of float4-copy
// roofline (~27.4 us). This version: one block per a-row; planes 0,1 staged
// to LDS with aligned float4 loads (row stride 6561 is odd -> per-row shift
// g&3 makes the quad grid 16B-aligned), butterfly computed at lane-stride-1
// from LDS (2 lanes/bank = free), plane 2 copied float4->uint4 without LDS.

constexpr int PLANE = 2187;          // 3^7
constexpr int TWO_PLANES = 4374;
constexpr int ROWLEN = 6561;         // 3^8
constexpr int NROWS = 2187;          // d_left

__device__ __forceinline__ uint32_t pack_bf2(float re, float im) {
    __hip_bfloat162 h;
    h.x = __float2bfloat16(im);      // low half  = imag (verified layout)
    h.y = __float2bfloat16(re);      // high half = real
    return *reinterpret_cast<uint32_t*>(&h);
}

__global__ __launch_bounds__(256, 4) void rot_kernel(
    const float* __restrict__ xr,
    const float* __restrict__ xi,
    const float* __restrict__ angle,
    uint32_t* __restrict__ out)
{
    __shared__ __align__(16) float s_xr[TWO_PLANES + 6];
    __shared__ __align__(16) float s_xi[TWO_PLANES + 6];

    const int tid = threadIdx.x;
    const int a   = blockIdx.x;
    const int g   = a * ROWLEN;              // row start (element index)

    const float half = 0.5f * angle[0];
    const float s = sinf(half);
    const float c = cosf(half);

    // ---- stage planes 0,1 (contiguous [g, g+4374)) into LDS, 16B-aligned ----
    const int off = g & 3;                   // LDS shift: l(e) = e + off
    const int pre = (4 - off) & 3;           // head elements before aligned quads
    const int nq  = (TWO_PLANES - pre) >> 2; // aligned quads
    // head (scalar)
    if (tid < pre) {
        s_xr[tid + off] = xr[g + tid];
        s_xi[tid + off] = xi[g + tid];
    }
    // body (float4 -> ds_write_b128; pre+off is 0 or 4 -> 16B-aligned LDS dst)
    const float4* gr = reinterpret_cast<const float4*>(xr + g + pre);
    const float4* gi = reinterpret_cast<const float4*>(xi + g + pre);
    float4* sr4 = reinterpret_cast<float4*>(&s_xr[pre + off]);
    float4* si4 = reinterpret_cast<float4*>(&s_xi[pre + off]);
    for (int q = tid; q < nq; q += 256) {
        sr4[q] = gr[q];
        si4[q] = gi[q];
    }
    // tail (scalar)
    {
        int e = pre + 4 * nq + tid;
        if (e < TWO_PLANES) {
            s_xr[e + off] = xr[g + e];
            s_xi[e + off] = xi[g + e];
        }
    }

    // ---- plane 2 passthrough (no LDS), overlaps the staging drain ----
    {
        const int g2   = g + TWO_PLANES;
        const int pre2 = (4 - (g2 & 3)) & 3;
        const int nq2  = (PLANE - pre2) >> 2;
        if (tid < pre2) {
            int idx = g2 + tid;
            out[idx] = pack_bf2(xr[idx], xi[idx]);
        }
        const float4* gr2 = reinterpret_cast<const float4*>(xr + g2 + pre2);
        const float4* gi2 = reinterpret_cast<const float4*>(xi + g2 + pre2);
        uint4* o4 = reinterpret_cast<uint4*>(out + g2 + pre2);
        for (int q = tid; q < nq2; q += 256) {
            float4 r = gr2[q];
            float4 i = gi2[q];
            uint4 o;
            o.x = pack_bf2(r.x, i.x);
            o.y = pack_bf2(r.y, i.y);
            o.z = pack_bf2(r.z, i.z);
            o.w = pack_bf2(r.w, i.w);
            o4[q] = o;
        }
        int e2 = pre2 + 4 * nq2 + tid;
        if (e2 < PLANE) {
            int idx = g2 + e2;
            out[idx] = pack_bf2(xr[idx], xi[idx]);
        }
    }

    __syncthreads();

    // ---- butterfly on planes 0,1 from LDS; lane-stride-1 (conflict-free) ----
    #pragma unroll
    for (int m = 0; m < 18; ++m) {           // 18*256 = 4608 >= 4374
        int e = tid + (m << 8);
        if (e < TWO_PLANES) {
            int p = e + ((e < PLANE) ? PLANE : -PLANE);
            float xre = s_xr[e + off], xie = s_xi[e + off];
            float xrp = s_xr[p + off], xip = s_xi[p + off];
            float yr = c * xre + s * xip;
            float yi = c * xie - s * xrp;
            out[g + e] = pack_bf2(yr, yi);
        }
    }
}

extern "C" void kernel_launch(void* const* d_in, const int* in_sizes, int n_in,
                              void* d_out, int out_size, void* d_ws, size_t ws_size,
                              hipStream_t stream) {
    // Inputs in setup_inputs() dict order: x_real (D), x_imag (D), angle (1).
    const float* big[2] = {nullptr, nullptr};
    const float* angle = nullptr;
    int nbig = 0;
    for (int i = 0; i < n_in; ++i) {
        if (in_sizes[i] == 1) angle = (const float*)d_in[i];
        else if (nbig < 2)    big[nbig++] = (const float*)d_in[i];
    }
    const float* xr = big[0];
    const float* xi = big[1];
    uint32_t* out = (uint32_t*)d_out;

    rot_kernel<<<NROWS, 256, 0, stream>>>(xr, xi, angle, out);
}